// Round 1
// 268.925 us; speedup vs baseline: 1.0254x; 1.0254x over previous
//
#include <hip/hip_runtime.h>
#include <hip/hip_bf16.h>
#include <stdint.h>

#define NB 4
#define NS 2048
#define ND 1024
#define NH 16
#define NHS 64
#define NEG_BIG (-1e30f)
// 1/sqrt(HS) * log2(e): folds softmax exp->exp2 into Q scaling (exactly softmax-invariant)
#define Q_SCALE 0.18033688011112042f

typedef __bf16 bf16x8 __attribute__((ext_vector_type(8)));
typedef float floatx4 __attribute__((ext_vector_type(4)));
typedef short s16x4 __attribute__((ext_vector_type(4)));

#if defined(__has_builtin)
#if __has_builtin(__builtin_amdgcn_mfma_f32_16x16x16bf16_1k)
#define HAVE_MFMA1K 1
#endif
#endif
#ifndef HAVE_MFMA1K
#define HAVE_MFMA1K 0
#endif

static constexpr size_t WSLAB = (size_t)NH * ND * NHS;        // 2^20 elems per weight mat
static constexpr size_t QSLAB = (size_t)NB * NH * NS * NHS;   // 8M elems per QKV/Y slab
static constexpr size_t XSLAB = (size_t)NB * NS * ND;         // 8M elems (x as bf16)

__device__ __forceinline__ uint16_t f2b(float f) {
    union { __hip_bfloat16 h; uint16_t u; } cv;
    cv.h = __float2bfloat16(f);
    return cv.u;
}

// async global->LDS, 16B per lane. LDS dest = wave-uniform base + lane*16 (UNPADDED only).
__device__ __forceinline__ void gll16(const void* g, void* l) {
  __builtin_amdgcn_global_load_lds(
      (__attribute__((address_space(1))) void*)(uintptr_t)g,
      (__attribute__((address_space(3))) void*)(uintptr_t)l,
      16, 0, 0);
}

// ---------------- kernel P: merged x-convert + weight convert/transpose ----------------
__global__ __launch_bounds__(256) void k_prep(
    const float* __restrict__ x, const float* __restrict__ Wq,
    const float* __restrict__ Wk, const float* __restrict__ Wv,
    const float* __restrict__ Wo, uint16_t* __restrict__ xb,
    uint16_t* __restrict__ wt) {
  __shared__ __align__(16) uint16_t T[64][72];
  int bid = blockIdx.x;
  int tid = threadIdx.x;
  if (bid < 4096) {
    size_t i0 = ((size_t)bid * 256 + tid) * 8;
    float4 f0 = *(const float4*)&x[i0];
    float4 f1 = *(const float4*)&x[i0 + 4];
    __align__(16) uint16_t tmp[8];
    tmp[0] = f2b(f0.x); tmp[1] = f2b(f0.y); tmp[2] = f2b(f0.z); tmp[3] = f2b(f0.w);
    tmp[4] = f2b(f1.x); tmp[5] = f2b(f1.y); tmp[6] = f2b(f1.z); tmp[7] = f2b(f1.w);
    *(uint4*)&xb[i0] = *(uint4*)tmp;
    return;
  }
  bid -= 4096;
  const float* src; uint16_t* dst;
  int srcStride, dstStride, r0, c0;
  if (bid < 768) {
    int mat = bid >> 8;
    int rem = bid & 255;
    int h = rem >> 4, dt = rem & 15;
    const float* W = (mat == 0) ? Wq : (mat == 1) ? Wk : Wv;
    src = W + (size_t)h * (ND * NHS);
    dst = wt + (size_t)mat * WSLAB + (size_t)h * (NHS * ND);
    srcStride = NHS; dstStride = ND;
    r0 = dt * 64; c0 = 0;
  } else {
    int rem = bid - 768;
    int dt = rem >> 4, et = rem & 15;
    src = Wo; dst = wt + 3 * WSLAB;
    srcStride = ND; dstStride = ND;
    r0 = dt * 64; c0 = et * 64;
  }
  for (int u = tid; u < 1024; u += 256) {
    int row = u >> 4, cq = u & 15;
    float4 f = *(const float4*)&src[(size_t)(r0 + row) * srcStride + c0 + cq * 4];
    uint16_t* p = &T[row][cq * 4];
    p[0] = f2b(f.x); p[1] = f2b(f.y); p[2] = f2b(f.z); p[3] = f2b(f.w);
  }
  __syncthreads();
  for (int u = tid; u < 512; u += 256) {
    int c = u >> 3, cg = u & 7;
    __align__(16) uint16_t tmp[8];
    for (int j = 0; j < 8; j++) tmp[j] = T[cg * 8 + j][c];
    *(uint4*)&dst[(size_t)(c0 + c) * dstStride + r0 + cg * 8] = *(uint4*)tmp;
  }
}

// ---------------- kernel 1: fused QKV GEMM, 256x256 8-phase counted-vmcnt ----------------
// Geometry: BM=BN=256, BK=64, 512 threads = 8 waves (2M x 4N), per-wave C = 128x64.
// LDS: ring of 8 slots x 16KiB. Half-tile h (global index, 4 per K-tile):
//   h = 4*t + {0:A-klo, 1:B-klo, 2:A-khi, 3:B-khi}; slot(h) = h & 7.
//   Each half = 256 rows x 32 K bf16, row-major (64B rows -> ds_read_b128 at bank floor,
//   no swizzle needed; avoids rule-21 global_load_lds swizzle trap).
// Schedule: 4 phases per K-tile (kk x qm). Phase: ds_read frags; issue stage of half
//   (phase+6) (1.5 tiles ahead, 2 gll16/thread); barrier; setprio(1); 16 MFMA; setprio(0);
//   [tile boundary only: vmcnt(4) -- newest 2 halves stay in flight; vmcnt(0) before last
//   tile]; barrier. Ring-slot lifetime: overwrite of slot(h) targets half h-8, whose last
//   read is >=2 barriers before the stage issue (verified for all phase residues).
__global__ __launch_bounds__(512, 2) void k_qkv(
    const uint16_t* __restrict__ xb, const uint16_t* __restrict__ wt,
    uint16_t* __restrict__ qkv) {
  __shared__ __align__(16) uint16_t L[8 * 8192];   // 128 KiB

  // XCD-aware bijective swizzle: 384 blocks, 8 XCDs, 48/XCD (384 % 8 == 0).
  int bid = blockIdx.x;
  int swz = (bid & 7) * 48 + (bid >> 3);
  int m0 = (swz & 31) * 256;        // 32 m-tiles fastest (B-panel stays in XCD L2)
  int n0 = (swz >> 5) * 256;        // 12 n-tiles

  int tid = threadIdx.x;
  int wave = tid >> 6, lane = tid & 63, quad = lane >> 4, l16 = lane & 15;
  int wr = wave >> 2, wc = wave & 3;

  // staging: chunk c = round*512 + tid covers (row = c>>2, 16B-col = c&3) of a half
  const uint16_t* pA = xb + (size_t)(m0 + (tid >> 2)) * ND + (tid & 3) * 8;
  const uint16_t* pB = wt + (size_t)(n0 + (tid >> 2)) * ND + (tid & 3) * 8;
  const int ldsStageOff = wave * 512;   // wave-uniform LDS base (u16); round1 at +4096

  // ds_read per-thread bases (u16 units within a 8192-u16 slot)
  const int offA = (wr * 128 + l16) * 32 + quad * 8;
  const int offB = (wc * 64 + l16) * 32 + quad * 8;

  floatx4 acc[8][4];
  #pragma unroll
  for (int i = 0; i < 8; i++)
    #pragma unroll
    for (int j = 0; j < 4; j++) acc[i][j] = (floatx4){0.f, 0.f, 0.f, 0.f};

#define STAGE(H)                                                                \
  do {                                                                          \
    int h_ = (H);                                                               \
    if (h_ < 64) {                                                              \
      const uint16_t* g_ = ((h_ & 1) ? pB : pA) + (h_ >> 2) * 64 + ((h_ >> 1) & 1) * 32; \
      uint16_t* l_ = &L[(h_ & 7) * 8192 + ldsStageOff];                         \
      gll16(g_, l_);                                                            \
      gll16(g_ + 128 * ND, l_ + 4096);                                          \
    }                                                                           \
  } while (0)

#define PH_BAR()                         \
  do {                                   \
    asm volatile("" ::: "memory");       \
    __builtin_amdgcn_s_barrier();        \
    asm volatile("" ::: "memory");       \
  } while (0)

  // prologue: stage halves 0..5 (tile0 complete + tile1 klo pair); drain oldest 4 halves
  STAGE(0); STAGE(1); STAGE(2); STAGE(3); STAGE(4); STAGE(5);
  asm volatile("s_waitcnt vmcnt(4)" ::: "memory");
  PH_BAR();

  bf16x8 bfr[4];   // B frags persist across the two qm phases of a kk

#define MFMA16(QM)                                                                                   \
  acc[(QM)*4+0][0] = __builtin_amdgcn_mfma_f32_16x16x32_bf16(af0_, bfr[0], acc[(QM)*4+0][0],0,0,0);  \
  acc[(QM)*4+0][1] = __builtin_amdgcn_mfma_f32_16x16x32_bf16(af0_, bfr[1], acc[(QM)*4+0][1],0,0,0);  \
  acc[(QM)*4+0][2] = __builtin_amdgcn_mfma_f32_16x16x32_bf16(af0_, bfr[2], acc[(QM)*4+0][2],0,0,0);  \
  acc[(QM)*4+0][3] = __builtin_amdgcn_mfma_f32_16x16x32_bf16(af0_, bfr[3], acc[(QM)*4+0][3],0,0,0);  \
  acc[(QM)*4+1][0] = __builtin_amdgcn_mfma_f32_16x16x32_bf16(af1_, bfr[0], acc[(QM)*4+1][0],0,0,0);  \
  acc[(QM)*4+1][1] = __builtin_amdgcn_mfma_f32_16x16x32_bf16(af1_, bfr[1], acc[(QM)*4+1][1],0,0,0);  \
  acc[(QM)*4+1][2] = __builtin_amdgcn_mfma_f32_16x16x32_bf16(af1_, bfr[2], acc[(QM)*4+1][2],0,0,0);  \
  acc[(QM)*4+1][3] = __builtin_amdgcn_mfma_f32_16x16x32_bf16(af1_, bfr[3], acc[(QM)*4+1][3],0,0,0);  \
  acc[(QM)*4+2][0] = __builtin_amdgcn_mfma_f32_16x16x32_bf16(af2_, bfr[0], acc[(QM)*4+2][0],0,0,0);  \
  acc[(QM)*4+2][1] = __builtin_amdgcn_mfma_f32_16x16x32_bf16(af2_, bfr[1], acc[(QM)*4+2][1],0,0,0);  \
  acc[(QM)*4+2][2] = __builtin_amdgcn_mfma_f32_16x16x32_bf16(af2_, bfr[2], acc[(QM)*4+2][2],0,0,0);  \
  acc[(QM)*4+2][3] = __builtin_amdgcn_mfma_f32_16x16x32_bf16(af2_, bfr[3], acc[(QM)*4+2][3],0,0,0);  \
  acc[(QM)*4+3][0] = __builtin_amdgcn_mfma_f32_16x16x32_bf16(af3_, bfr[0], acc[(QM)*4+3][0],0,0,0);  \
  acc[(QM)*4+3][1] = __builtin_amdgcn_mfma_f32_16x16x32_bf16(af3_, bfr[1], acc[(QM)*4+3][1],0,0,0);  \
  acc[(QM)*4+3][2] = __builtin_amdgcn_mfma_f32_16x16x32_bf16(af3_, bfr[2], acc[(QM)*4+3][2],0,0,0);  \
  acc[(QM)*4+3][3] = __builtin_amdgcn_mfma_f32_16x16x32_bf16(af3_, bfr[3], acc[(QM)*4+3][3],0,0,0)

#define PHASE(T4, KK, QM, HSTAGE, LOADB)                                        \
  {                                                                             \
    const int slA_ = (((T4) + 2 * (KK)) & 7) * 8192;                            \
    bf16x8 af0_ = *(const bf16x8*)&L[slA_ + offA + (QM) * 2048 + 0 * 512];      \
    bf16x8 af1_ = *(const bf16x8*)&L[slA_ + offA + (QM) * 2048 + 1 * 512];      \
    bf16x8 af2_ = *(const bf16x8*)&L[slA_ + offA + (QM) * 2048 + 2 * 512];      \
    bf16x8 af3_ = *(const bf16x8*)&L[slA_ + offA + (QM) * 2048 + 3 * 512];      \
    if (LOADB) {                                                                \
      const int slB_ = (((T4) + 2 * (KK) + 1) & 7) * 8192;                      \
      bfr[0] = *(const bf16x8*)&L[slB_ + offB + 0 * 512];                       \
      bfr[1] = *(const bf16x8*)&L[slB_ + offB + 1 * 512];                       \
      bfr[2] = *(const bf16x8*)&L[slB_ + offB + 2 * 512];                       \
      bfr[3] = *(const bf16x8*)&L[slB_ + offB + 3 * 512];                       \
    }                                                                           \
    STAGE(HSTAGE);                                                              \
    PH_BAR();                                                                   \
    __builtin_amdgcn_s_setprio(1);                                              \
    MFMA16(QM);                                                                 \
    __builtin_amdgcn_s_setprio(0);                                              \
  }

  for (int t = 0; t < 16; ++t) {
    int t4 = t * 4;
    PHASE(t4, 0, 0, t4 + 6, 1);
    PH_BAR();
    PHASE(t4, 0, 1, t4 + 7, 0);
    PH_BAR();
    PHASE(t4, 1, 0, t4 + 8, 1);
    PH_BAR();
    PHASE(t4, 1, 1, t4 + 9, 0);
    // tile-boundary wait: keep newest 2 halves (4 loads) in flight; full drain before last
    if (t < 14)       { asm volatile("s_waitcnt vmcnt(4)" ::: "memory"); }
    else if (t == 14) { asm volatile("s_waitcnt vmcnt(0)" ::: "memory"); }
    PH_BAR();
  }
#undef PHASE
#undef MFMA16
#undef STAGE
#undef PH_BAR

  // epilogue: scatter to [mat][b,h,s,e] with Q pre-scale
  int matid = n0 >> 10;
  float scale = (matid == 0) ? Q_SCALE : 1.0f;
  uint16_t* base = qkv + (size_t)matid * QSLAB;
  int hh = ((n0 & 1023) >> 6) + wc;      // one head per wave-column (64 cols)
  #pragma unroll
  for (int mq = 0; mq < 8; mq++) {
    int m = m0 + wr * 128 + mq * 16 + quad * 4;
    int b = m >> 11, s = m & 2047;
    size_t rbase = ((size_t)(b * 16 + hh) * NS + s) * NHS;
    #pragma unroll
    for (int nt = 0; nt < 4; nt++)
      #pragma unroll
      for (int r = 0; r < 4; r++)
        base[rbase + (size_t)r * NHS + nt * 16 + l16] = f2b(acc[mq][nt][r] * scale);
  }
}

// ---------------- kernel 1b: V -> V^T ([B,H,S,HS] -> [B,H,HS,S]) ----------------
__global__ __launch_bounds__(256) void k_vt(
    const uint16_t* __restrict__ v, uint16_t* __restrict__ vt) {
  __shared__ __align__(16) uint16_t T[64][72];
  int bh = blockIdx.y;
  int s0 = blockIdx.x * 64;
  int tid = threadIdx.x;
  const uint16_t* src = v + (size_t)bh * (NS * NHS);
  uint16_t* dst = vt + (size_t)bh * (NS * NHS);
  for (int u = tid; u < 512; u += 256) {
    int row = u >> 3, cg = u & 7;
    *(uint4*)&T[row][cg * 8] =
        *(const uint4*)&src[(size_t)(s0 + row) * NHS + cg * 8];
  }
  __syncthreads();
  for (int u = tid; u < 512; u += 256) {
    int e = u >> 3, cg = u & 7;
    __align__(16) uint16_t tmp[8];
    for (int j = 0; j < 8; j++) tmp[j] = T[cg * 8 + j][e];
    *(uint4*)&dst[(size_t)e * NS + s0 + cg * 8] = *(uint4*)tmp;
  }
}

#if HAVE_MFMA1K
// ---------------- kernel 2: causal attention, S^T trick + reg-prefetch double-buffer ----------------
// S^T = K.Q^T puts P^T directly in B-operand layout of 16x16x16 MFMA; O^T = V^T.P^T in regs.
// K/V^T tile kt+1 prefetched into VGPRs while computing tile kt; regs flushed to padded
// LDS between barriers. Global-load latency overlaps the whole compute phase.
__global__ __launch_bounds__(256, 4) void k_attn(
    const uint16_t* __restrict__ Q, const uint16_t* __restrict__ K,
    const uint16_t* __restrict__ VT, uint16_t* __restrict__ Y) {
  __shared__ __align__(16) uint16_t Ks[64][72];   // [key][e]
  __shared__ __align__(16) uint16_t Vs[64][72];   // [e][key]
  int bh = blockIdx.y;
  int b = bh >> 4, h = bh & 15;
  int ta = blockIdx.x;       // 0..15
  int tb = 31 - ta;          // 16..31
  const uint16_t* Qp = Q + (size_t)bh * (NS * NHS);
  const uint16_t* Kp = K + (size_t)bh * (NS * NHS);
  const uint16_t* Vp = VT + (size_t)bh * (NS * NHS);  // [e][key]
  int tid = threadIdx.x;
  int wv = tid >> 6, lane = tid & 63, quad = lane >> 4, l16 = lane & 15;

  // staging map: each thread covers u = tid and tid+256 (row = u>>3, 16B col = u&7)
  int row0 = tid >> 3, cg0 = tid & 7;
  int row1 = (tid + 256) >> 3, cg1 = tid & 7;

  // Q fragments from global; B operand of S^T = K.Q^T (n = q-row = l16)
  int rA = ta * 64 + wv * 16 + l16;
  int rB = tb * 64 + wv * 16 + l16;
  bf16x8 aqA0 = *(const bf16x8*)&Qp[(size_t)rA * NHS + quad * 8];
  bf16x8 aqA1 = *(const bf16x8*)&Qp[(size_t)rA * NHS + 32 + quad * 8];
  bf16x8 aqB0 = *(const bf16x8*)&Qp[(size_t)rB * NHS + quad * 8];
  bf16x8 aqB1 = *(const bf16x8*)&Qp[(size_t)rB * NHS + 32 + quad * 8];

  float lAs = 0.f, lBs = 0.f;          // per-lane row-sum (all p of a lane share q-row l16)
  floatx4 oA[4], oB[4];                // O^T accumulators, one per e-tile
  for (int et = 0; et < 4; et++) {
    oA[et] = (floatx4){0.f, 0.f, 0.f, 0.f};
    oB[et] = (floatx4){0.f, 0.f, 0.f, 0.f};
  }

  // prefetch tile 0 into registers
  uint4 rk0, rk1, rv0, rv1;
  rk0 = *(const uint4*)&Kp[(size_t)(0 * 64 + row0) * NHS + cg0 * 8];
  rk1 = *(const uint4*)&Kp[(size_t)(0 * 64 + row1) * NHS + cg1 * 8];
  rv0 = *(const uint4*)&Vp[(size_t)row0 * NS + 0 * 64 + cg0 * 8];
  rv1 = *(const uint4*)&Vp[(size_t)row1 * NS + 0 * 64 + cg1 * 8];

  for (int kt = 0; kt <= tb; kt++) {
    bool doA = (kt <= ta);  // uniform across block
    __syncthreads();        // readers of previous tile done
    *(uint4*)&Ks[row0][cg0 * 8] = rk0;
    *(uint4*)&Ks[row1][cg1 * 8] = rk1;
    *(uint4*)&Vs[row0][cg0 * 8] = rv0;
    *(uint4*)&Vs[row1][cg1 * 8] = rv1;
    __syncthreads();        // tile kt visible
    if (kt < tb) {          // issue prefetch of kt+1; consumed after next barrier
      rk0 = *(const uint4*)&Kp[(size_t)((kt + 1) * 64 + row0) * NHS + cg0 * 8];
      rk1 = *(const uint4*)&Kp[(size_t)((kt + 1) * 64 + row1) * NHS + cg1 * 8];
      rv0 = *(const uint4*)&Vp[(size_t)row0 * NS + (kt + 1) * 64 + cg0 * 8];
      rv1 = *(const uint4*)&Vp[(size_t)row1 * NS + (kt + 1) * 64 + cg1 * 8];
    }

    // ---- S^T tiles + mask + exp2 + pack (P^T lands in B-layout of K=16 MFMA) ----
    s16x4 pbA[4], pbB[4];
    for (int ct = 0; ct < 4; ct++) {
      bf16x8 kb0 = *(const bf16x8*)&Ks[ct * 16 + l16][quad * 8];
      bf16x8 kb1 = *(const bf16x8*)&Ks[ct * 16 + l16][32 + quad * 8];
      int key = kt * 64 + ct * 16 + quad * 4;
      floatx4 c = (floatx4){0.f, 0.f, 0.f, 0.f};
      c = __builtin_amdgcn_mfma_f32_16x16x32_bf16(kb0, aqB0, c, 0, 0, 0);
      c = __builtin_amdgcn_mfma_f32_16x16x32_bf16(kb1, aqB1, c, 0, 0, 0);
      for (int r = 0; r < 4; r++) {
        float s = (kt == tb && key + r > rB) ? NEG_BIG : c[r];
        float p = __builtin_amdgcn_exp2f(s);
        lBs += p;
        pbB[ct][r] = (short)f2b(p);
      }
      if (doA) {
        floatx4 d = (floatx4){0.f, 0.f, 0.f, 0.f};
        d = __builtin_amdgcn_mfma_f32_16x16x32_bf16(kb0, aqA0, d, 0, 0, 0);
        d = __builtin_amdgcn_mfma_f32_16x16x32_bf16(kb1, aqA1, d, 0, 0, 0);
        for (int r = 0; r < 4; r++) {
          float s = (kt == ta && key + r > rA) ? NEG_BIG : d[r];
          float p = __builtin_amdgcn_exp2f(s);
          lAs += p;
          pbA[ct][r] = (short)f2b(p);
        }
      }
    }
    // ---- O^T += V^T . P^T (A-frag = 4 keys of V^T via ds_read_b64, shared A/B) ----
    for (int et = 0; et < 4; et++)
      for (int ct = 0; ct < 4; ct++) {
        s16x4 va = *(const s16x4*)&Vs[et * 16 + l16][ct * 16 + quad * 4];
        oB[et] = __builtin_amdgcn_mfma_f32_16x16x16bf16_1k(va, pbB[ct], oB[et], 0, 0, 0);
        if (doA)
          oA[et] = __builtin_amdgcn_mfma_f32_16x16x16bf16_1k(va, pbA[ct], oA[et], 0, 0, 0);
      }
  }
  // ---- reduce row-sums across the 4 quads, normalize, packed store ----
  lAs += __shfl_xor(lAs, 16, 64); lAs += __shfl_xor(lAs, 32, 64);
  lBs += __shfl_xor(lBs, 16, 64); lBs += __shfl_xor(lBs, 32, 64);
  float invA = 1.f / lAs, invB = 1.f / lBs;
  uint16_t* yb = Y + (size_t)b * NS * ND + (size_t)h * NHS;
  for (int et = 0; et < 4; et++) {
    __align__(8) uint16_t tA[4], tB[4];
    for (int r = 0; r < 4; r++) {
      tA[r] = f2b(oA[et][r] * invA);
      tB[r] = f2b(oB[et][r] * invB);
    }
    *(uint2*)&yb[(size_t)rA * ND + et * 16 + quad * 4] = *(uint2*)tA;
    *(uint2*)&yb[(size_t)rB * ND + et * 16 + quad * 4] = *(uint2*)tB;
  }
}
#else
// ---------------- fallback: round-8 k_attn (LDS-staged K/V + P round-trip) ----------------
__global__ __launch_bounds__(256) void k_attn(
    const uint16_t* __restrict__ Q, const uint16_t* __restrict__ K,
    const uint16_t* __restrict__ VT, uint16_t* __restrict__ Y) {
  __shared__ __align__(16) uint16_t Ks[64][72];
  __shared__ __align__(16) uint16_t Vs[64][72];
  __shared__ __align__(16) uint16_t Ps[4][2][16][72];
  int bh = blockIdx.y;
  int b = bh >> 4, h = bh & 15;
  int ta = blockIdx.x;
  int tb = 31 - ta;
  const uint16_t* Qp = Q + (size_t)bh * (NS * NHS);
  const uint16_t* Kp = K + (size_t)bh * (NS * NHS);
  const uint16_t* Vp = VT + (size_t)bh * (NS * NHS);
  int tid = threadIdx.x;
  int wv = tid >> 6, lane = tid & 63, quad = lane >> 4, l16 = lane & 15;

  int rA = ta * 64 + wv * 16 + l16;
  int rB = tb * 64 + wv * 16 + l16;
  bf16x8 aqA0 = *(const bf16x8*)&Qp[(size_t)rA * NHS + quad * 8];
  bf16x8 aqA1 = *(const bf16x8*)&Qp[(size_t)rA * NHS + 32 + quad * 8];
  bf16x8 aqB0 = *(const bf16x8*)&Qp[(size_t)rB * NHS + quad * 8];
  bf16x8 aqB1 = *(const bf16x8*)&Qp[(size_t)rB * NHS + 32 + quad * 8];

  float lA[4] = {0.f, 0.f, 0.f, 0.f}, lB[4] = {0.f, 0.f, 0.f, 0.f};
  floatx4 oA[4], oB[4];
  for (int ct = 0; ct < 4; ct++) {
    oA[ct] = (floatx4){0.f, 0.f, 0.f, 0.f};
    oB[ct] = (floatx4){0.f, 0.f, 0.f, 0.f};
  }
  for (int kt = 0; kt <= tb; kt++) {
    bool doA = (kt <= ta);
    __syncthreads();
    for (int u = tid; u < 512; u += 256) {
      int row = u >> 3, cg = u & 7;
      *(uint4*)&Ks[row][cg * 8] =
          *(const uint4*)&Kp[(size_t)(kt * 64 + row) * NHS + cg * 8];
    }
    for (int u = tid; u < 512; u += 256) {
      int row = u >> 3, cg = u & 7;
      *(uint4*)&Vs[row][cg * 8] =
          *(const uint4*)&Vp[(size_t)row * NS + kt * 64 + cg * 8];
    }
    __syncthreads();
    floatx4 sA[4], sB[4];
    for (int ct = 0; ct < 4; ct++) {
      bf16x8 kb0 = *(const bf16x8*)&Ks[ct * 16 + l16][quad * 8];
      bf16x8 kb1 = *(const bf16x8*)&Ks[ct * 16 + l16][32 + quad * 8];
      floatx4 c = (floatx4){0.f, 0.f, 0.f, 0.f};
      c = __builtin_amdgcn_mfma_f32_16x16x32_bf16(aqB0, kb0, c, 0, 0, 0);
      c = __builtin_amdgcn_mfma_f32_16x16x32_bf16(aqB1, kb1, c, 0, 0, 0);
      sB[ct] = c;
      if (doA) {
        floatx4 d = (floatx4){0.f, 0.f, 0.f, 0.f};
        d = __builtin_amdgcn_mfma_f32_16x16x32_bf16(aqA0, kb0, d, 0, 0, 0);
        d = __builtin_amdgcn_mfma_f32_16x16x32_bf16(aqA1, kb1, d, 0, 0, 0);
        sA[ct] = d;
      }
    }
    if (kt == tb) {
      int qrb = tb * 64 + wv * 16 + quad * 4;
      for (int ct = 0; ct < 4; ct++) {
        int kg = kt * 64 + ct * 16 + l16;
        for (int r = 0; r < 4; r++)
          sB[ct][r] = (kg <= qrb + r) ? sB[ct][r] : NEG_BIG;
      }
    }
    if (doA && kt == ta) {
      int qrb = ta * 64 + wv * 16 + quad * 4;
      for (int ct = 0; ct < 4; ct++) {
        int kg = kt * 64 + ct * 16 + l16;
        for (int r = 0; r < 4; r++)
          sA[ct][r] = (kg <= qrb + r) ? sA[ct][r] : NEG_BIG;
      }
    }
    for (int ct = 0; ct < 4; ct++)
      for (int r = 0; r < 4; r++) {
        float p = __builtin_amdgcn_exp2f(sB[ct][r]);
        lB[r] += p;
        Ps[wv][1][quad * 4 + r][ct * 16 + l16] = f2b(p);
      }
    if (doA)
      for (int ct = 0; ct < 4; ct++)
        for (int r = 0; r < 4; r++) {
          float p = __builtin_amdgcn_exp2f(sA[ct][r]);
          lA[r] += p;
          Ps[wv][0][quad * 4 + r][ct * 16 + l16] = f2b(p);
        }
    bf16x8 apB0 = *(const bf16x8*)&Ps[wv][1][l16][quad * 8];
    bf16x8 apB1 = *(const bf16x8*)&Ps[wv][1][l16][32 + quad * 8];
    bf16x8 apA0, apA1;
    if (doA) {
      apA0 = *(const bf16x8*)&Ps[wv][0][l16][quad * 8];
      apA1 = *(const bf16x8*)&Ps[wv][0][l16][32 + quad * 8];
    }
    for (int ct = 0; ct < 4; ct++) {
      bf16x8 vb0 = *(const bf16x8*)&Vs[ct * 16 + l16][quad * 8];
      bf16x8 vb1 = *(const bf16x8*)&Vs[ct * 16 + l16][32 + quad * 8];
      oB[ct] = __builtin_amdgcn_mfma_f32_16x16x32_bf16(apB0, vb0, oB[ct], 0, 0, 0);
      oB[ct] = __builtin_amdgcn_mfma_f32_16x16x32_bf16(apB1, vb1, oB[ct], 0, 0, 0);
      if (doA) {
        oA[ct] = __builtin_amdgcn_mfma_f32_16x16x32_bf16(apA0, vb0, oA[ct], 0, 0, 0);
        oA[ct] = __builtin_amdgcn_mfma_f32_16x16x32_bf16(apA1, vb1, oA[ct], 0, 0, 0);
      }
    }
  }
  for (int off = 1; off < 16; off <<= 1)
    for (int r = 0; r < 4; r++) {
      lA[r] += __shfl_xor(lA[r], off, 64);
      lB[r] += __shfl_xor(lB[r], off, 64);
    }
  uint16_t* yb = Y + (size_t)b * NS * ND + (size_t)h * NHS;
  for (int ct = 0; ct < 4; ct++)
    for (int r = 0; r < 4; r++) {
      int sA_ = ta * 64 + wv * 16 + quad * 4 + r;
      int sB_ = tb * 64 + wv * 16 + quad * 4 + r;
      yb[(size_t)sA_ * ND + ct * 16 + l16] = f2b(oA[ct][r] / lA[r]);
      yb[(size_t)sB_ * ND + ct * 16 + l16] = f2b(oB[ct][r] / lB[r]);
    }
}
#endif

// ---------------- kernel 3: output projection + bias, m97-style (fp32 out) ----------------
__global__ __launch_bounds__(256) void k_proj(
    const uint16_t* __restrict__ y, const uint16_t* __restrict__ wot,
    const float* __restrict__ bo, float* __restrict__ out) {
  __shared__ __align__(16) uint16_t As[128 * 64];
  __shared__ __align__(16) uint16_t Bs[128 * 64];
  int m0 = blockIdx.x * 128;
  int n0 = blockIdx.y * 128;
  int tid = threadIdx.x;
  int wv = tid >> 6, lane = tid & 63, quad = lane >> 4, l16 = lane & 15;
  int wr = wv >> 1, wc = wv & 1;
  int srow = lane >> 3, scol = lane & 7;

  floatx4 acc[4][4];
  for (int i = 0; i < 4; i++)
    for (int j = 0; j < 4; j++) acc[i][j] = (floatx4){0.f, 0.f, 0.f, 0.f};

  for (int k0 = 0; k0 < ND; k0 += 64) {
    __syncthreads();
    for (int j = 0; j < 4; j++) {
      int rg = wv * 4 + j;
      int r = rg * 8 + srow;
      gll16(&y[(size_t)(m0 + r) * ND + k0 + scol * 8], &As[rg * 512]);
      gll16(&wot[(size_t)(n0 + r) * ND + k0 + scol * 8], &Bs[rg * 512]);
    }
    __syncthreads();
    for (int kk = 0; kk < 2; kk++) {
      bf16x8 af[4], bfr[4];
      for (int t = 0; t < 4; t++) {
        af[t]  = *(const bf16x8*)&As[(wr * 64 + t * 16 + l16) * 64 + kk * 32 + quad * 8];
        bfr[t] = *(const bf16x8*)&Bs[(wc * 64 + t * 16 + l16) * 64 + kk * 32 + quad * 8];
      }
      for (int mt = 0; mt < 4; mt++)
        for (int nt = 0; nt < 4; nt++)
          acc[mt][nt] = __builtin_amdgcn_mfma_f32_16x16x32_bf16(af[mt], bfr[nt], acc[mt][nt], 0, 0, 0);
    }
  }
  for (int mt = 0; mt < 4; mt++)
    for (int nt = 0; nt < 4; nt++)
      for (int r = 0; r < 4; r++) {
        int s = m0 + wr * 64 + mt * 16 + quad * 4 + r;
        int n = n0 + wc * 64 + nt * 16 + l16;
        out[(size_t)s * ND + n] = acc[mt][nt][r] + bo[n];
      }
}

extern "C" void kernel_launch(void* const* d_in, const int* in_sizes, int n_in,
                              void* d_out, int out_size, void* d_ws, size_t ws_size,
                              hipStream_t stream) {
  const float* x  = (const float*)d_in[0];
  const float* Wq = (const float*)d_in[1];
  const float* Wk = (const float*)d_in[2];
  const float* Wv = (const float*)d_in[3];
  const float* Wo = (const float*)d_in[4];
  const float* bo = (const float*)d_in[5];
  uint16_t* ws = (uint16_t*)d_ws;

  uint16_t* wt = ws;                       // 4 * WSLAB bf16 (Wq_t, Wk_t, Wv_t, Wo_t)
  uint16_t* xb = ws + 4 * WSLAB;           // XSLAB bf16
  uint16_t* q  = xb + XSLAB;               // QSLAB each
  uint16_t* k  = q + QSLAB;
  uint16_t* v  = k + QSLAB;
  uint16_t* y  = v + QSLAB;
  uint16_t* vt = y + QSLAB;                // QSLAB (V transposed)

  k_prep<<<dim3(5120), dim3(256), 0, stream>>>(x, Wq, Wk, Wv, Wo, xb, wt);
  k_qkv<<<dim3(384), dim3(512), 0, stream>>>(xb, wt, q);
  k_vt<<<dim3(NS / 64, NB * NH), dim3(256), 0, stream>>>(v, vt);
  k_attn<<<dim3(16, NB * NH), dim3(256), 0, stream>>>(q, k, vt, y);
  k_proj<<<dim3(64, 8), dim3(256), 0, stream>>>(y, wt + 3 * WSLAB, bo, (float*)d_out);
}

// Round 2
// 263.543 us; speedup vs baseline: 1.0463x; 1.0204x over previous
//
#include <hip/hip_runtime.h>
#include <hip/hip_bf16.h>
#include <stdint.h>

#define NB 4
#define NS 2048
#define ND 1024
#define NH 16
#define NHS 64
#define NEG_BIG (-1e30f)
// 1/sqrt(HS) * log2(e): folds softmax exp->exp2 into Q scaling (exactly softmax-invariant)
#define Q_SCALE 0.18033688011112042f

typedef __bf16 bf16x8 __attribute__((ext_vector_type(8)));
typedef float floatx4 __attribute__((ext_vector_type(4)));
typedef short s16x4 __attribute__((ext_vector_type(4)));

#if defined(__has_builtin)
#if __has_builtin(__builtin_amdgcn_mfma_f32_16x16x16bf16_1k)
#define HAVE_MFMA1K 1
#endif
#endif
#ifndef HAVE_MFMA1K
#define HAVE_MFMA1K 0
#endif

static constexpr size_t WSLAB = (size_t)NH * ND * NHS;        // 2^20 elems per weight mat
static constexpr size_t QSLAB = (size_t)NB * NH * NS * NHS;   // 8M elems per QKV/Y slab
static constexpr size_t XSLAB = (size_t)NB * NS * ND;         // 8M elems (x as bf16)

__device__ __forceinline__ uint16_t f2b(float f) {
    union { __hip_bfloat16 h; uint16_t u; } cv;
    cv.h = __float2bfloat16(f);
    return cv.u;
}

// async global->LDS, 16B per lane. LDS dest = wave-uniform base + lane*16 (UNPADDED only).
__device__ __forceinline__ void gll16(const void* g, void* l) {
  __builtin_amdgcn_global_load_lds(
      (__attribute__((address_space(1))) void*)(uintptr_t)g,
      (__attribute__((address_space(3))) void*)(uintptr_t)l,
      16, 0, 0);
}

// ---------------- kernel P: merged x-convert + weight convert/transpose ----------------
__global__ __launch_bounds__(256) void k_prep(
    const float* __restrict__ x, const float* __restrict__ Wq,
    const float* __restrict__ Wk, const float* __restrict__ Wv,
    const float* __restrict__ Wo, uint16_t* __restrict__ xb,
    uint16_t* __restrict__ wt) {
  __shared__ __align__(16) uint16_t T[64][72];
  int bid = blockIdx.x;
  int tid = threadIdx.x;
  if (bid < 4096) {
    size_t i0 = ((size_t)bid * 256 + tid) * 8;
    float4 f0 = *(const float4*)&x[i0];
    float4 f1 = *(const float4*)&x[i0 + 4];
    __align__(16) uint16_t tmp[8];
    tmp[0] = f2b(f0.x); tmp[1] = f2b(f0.y); tmp[2] = f2b(f0.z); tmp[3] = f2b(f0.w);
    tmp[4] = f2b(f1.x); tmp[5] = f2b(f1.y); tmp[6] = f2b(f1.z); tmp[7] = f2b(f1.w);
    *(uint4*)&xb[i0] = *(uint4*)tmp;
    return;
  }
  bid -= 4096;
  const float* src; uint16_t* dst;
  int srcStride, dstStride, r0, c0;
  if (bid < 768) {
    int mat = bid >> 8;
    int rem = bid & 255;
    int h = rem >> 4, dt = rem & 15;
    const float* W = (mat == 0) ? Wq : (mat == 1) ? Wk : Wv;
    src = W + (size_t)h * (ND * NHS);
    dst = wt + (size_t)mat * WSLAB + (size_t)h * (NHS * ND);
    srcStride = NHS; dstStride = ND;
    r0 = dt * 64; c0 = 0;
  } else {
    int rem = bid - 768;
    int dt = rem >> 4, et = rem & 15;
    src = Wo; dst = wt + 3 * WSLAB;
    srcStride = ND; dstStride = ND;
    r0 = dt * 64; c0 = et * 64;
  }
  for (int u = tid; u < 1024; u += 256) {
    int row = u >> 4, cq = u & 15;
    float4 f = *(const float4*)&src[(size_t)(r0 + row) * srcStride + c0 + cq * 4];
    uint16_t* p = &T[row][cq * 4];
    p[0] = f2b(f.x); p[1] = f2b(f.y); p[2] = f2b(f.z); p[3] = f2b(f.w);
  }
  __syncthreads();
  for (int u = tid; u < 512; u += 256) {
    int c = u >> 3, cg = u & 7;
    __align__(16) uint16_t tmp[8];
    for (int j = 0; j < 8; j++) tmp[j] = T[cg * 8 + j][c];
    *(uint4*)&dst[(size_t)(c0 + c) * dstStride + r0 + cg * 8] = *(uint4*)tmp;
  }
}

// ---------------- kernel 1: fused QKV GEMM, 256x256 8-phase counted-vmcnt ----------------
// Geometry: BM=BN=256, BK=64, 512 threads = 8 waves (2M x 4N), per-wave C = 128x64.
// LDS: ring of 8 slots x 8704 u16 (data 8192 u16 = 256 rows x 32 K bf16, row-major; 64B
//   rows -> ds_read_b128 at bank floor, no swizzle). Slot stride 8704 (17408B) keeps slot
//   bases bank-0-aligned (4352 words % 32 == 0) and leaves room for the V-transpose
//   epilogue buffer (64 e x 136 u16 per wave).
// XCD swizzle (L2 fix, round-1 post-mortem): bid&7 = XCD; each XCD owns a chunk of
//   4 m-tiles x 12 n-tiles, m-INNER n-OUTER, so its 2MB of A-panels stays L2-resident
//   across all n-sweeps and 6MB of B streams once. (m-fastest across the whole grid
//   streamed all 16MB of A per XCD: measured FETCH 103.5MB, latency-bound stalls.)
// Schedule: 4 phases/K-tile; per phase {ds_read frags; STAGE half (phase+6); barrier;
//   setprio(1); 16 MFMA; setprio(0); barrier}; counted vmcnt(4) once per K-tile.
__global__ __launch_bounds__(512, 2) void k_qkv(
    const uint16_t* __restrict__ xb, const uint16_t* __restrict__ wt,
    uint16_t* __restrict__ qk, uint16_t* __restrict__ vt) {
  __shared__ __align__(16) uint16_t L[8 * 8704];   // 139264 B

  int bid = blockIdx.x;
  int xcd = bid & 7, idx = bid >> 3;     // 48 tiles per XCD chunk
  int mt = xcd * 4 + (idx & 3);          // 4 m-tiles per XCD, inner
  int ntile = idx >> 2;                  // 12 n-tiles, outer
  int m0 = mt * 256;
  int n0 = ntile * 256;

  int tid = threadIdx.x;
  int wave = tid >> 6, lane = tid & 63, quad = lane >> 4, l16 = lane & 15;
  int wr = wave >> 2, wc = wave & 3;

  // staging: chunk c = round*512 + tid covers (row = c>>2, 16B-col = c&3) of a half
  const uint16_t* pA = xb + (size_t)(m0 + (tid >> 2)) * ND + (tid & 3) * 8;
  const uint16_t* pB = wt + (size_t)(n0 + (tid >> 2)) * ND + (tid & 3) * 8;
  const int ldsStageOff = wave * 512;   // wave-uniform LDS base (u16); round1 at +4096

  // ds_read per-thread bases (u16 units within a slot's 8192-u16 data region)
  const int offA = (wr * 128 + l16) * 32 + quad * 8;
  const int offB = (wc * 64 + l16) * 32 + quad * 8;

  floatx4 acc[8][4];
  #pragma unroll
  for (int i = 0; i < 8; i++)
    #pragma unroll
    for (int j = 0; j < 4; j++) acc[i][j] = (floatx4){0.f, 0.f, 0.f, 0.f};

#define STAGE(H)                                                                \
  do {                                                                          \
    int h_ = (H);                                                               \
    if (h_ < 64) {                                                              \
      const uint16_t* g_ = ((h_ & 1) ? pB : pA) + (h_ >> 2) * 64 + ((h_ >> 1) & 1) * 32; \
      uint16_t* l_ = &L[(h_ & 7) * 8704 + ldsStageOff];                         \
      gll16(g_, l_);                                                            \
      gll16(g_ + 128 * ND, l_ + 4096);                                          \
    }                                                                           \
  } while (0)

#define PH_BAR()                         \
  do {                                   \
    asm volatile("" ::: "memory");       \
    __builtin_amdgcn_s_barrier();        \
    asm volatile("" ::: "memory");       \
  } while (0)

  // prologue: stage halves 0..5 (tile0 complete + tile1 klo pair); drain oldest 4 halves
  STAGE(0); STAGE(1); STAGE(2); STAGE(3); STAGE(4); STAGE(5);
  asm volatile("s_waitcnt vmcnt(4)" ::: "memory");
  PH_BAR();

  bf16x8 bfr[4];   // B frags persist across the two qm phases of a kk

#define MFMA16(QM)                                                                                   \
  acc[(QM)*4+0][0] = __builtin_amdgcn_mfma_f32_16x16x32_bf16(af0_, bfr[0], acc[(QM)*4+0][0],0,0,0);  \
  acc[(QM)*4+0][1] = __builtin_amdgcn_mfma_f32_16x16x32_bf16(af0_, bfr[1], acc[(QM)*4+0][1],0,0,0);  \
  acc[(QM)*4+0][2] = __builtin_amdgcn_mfma_f32_16x16x32_bf16(af0_, bfr[2], acc[(QM)*4+0][2],0,0,0);  \
  acc[(QM)*4+0][3] = __builtin_amdgcn_mfma_f32_16x16x32_bf16(af0_, bfr[3], acc[(QM)*4+0][3],0,0,0);  \
  acc[(QM)*4+1][0] = __builtin_amdgcn_mfma_f32_16x16x32_bf16(af1_, bfr[0], acc[(QM)*4+1][0],0,0,0);  \
  acc[(QM)*4+1][1] = __builtin_amdgcn_mfma_f32_16x16x32_bf16(af1_, bfr[1], acc[(QM)*4+1][1],0,0,0);  \
  acc[(QM)*4+1][2] = __builtin_amdgcn_mfma_f32_16x16x32_bf16(af1_, bfr[2], acc[(QM)*4+1][2],0,0,0);  \
  acc[(QM)*4+1][3] = __builtin_amdgcn_mfma_f32_16x16x32_bf16(af1_, bfr[3], acc[(QM)*4+1][3],0,0,0);  \
  acc[(QM)*4+2][0] = __builtin_amdgcn_mfma_f32_16x16x32_bf16(af2_, bfr[0], acc[(QM)*4+2][0],0,0,0);  \
  acc[(QM)*4+2][1] = __builtin_amdgcn_mfma_f32_16x16x32_bf16(af2_, bfr[1], acc[(QM)*4+2][1],0,0,0);  \
  acc[(QM)*4+2][2] = __builtin_amdgcn_mfma_f32_16x16x32_bf16(af2_, bfr[2], acc[(QM)*4+2][2],0,0,0);  \
  acc[(QM)*4+2][3] = __builtin_amdgcn_mfma_f32_16x16x32_bf16(af2_, bfr[3], acc[(QM)*4+2][3],0,0,0);  \
  acc[(QM)*4+3][0] = __builtin_amdgcn_mfma_f32_16x16x32_bf16(af3_, bfr[0], acc[(QM)*4+3][0],0,0,0);  \
  acc[(QM)*4+3][1] = __builtin_amdgcn_mfma_f32_16x16x32_bf16(af3_, bfr[1], acc[(QM)*4+3][1],0,0,0);  \
  acc[(QM)*4+3][2] = __builtin_amdgcn_mfma_f32_16x16x32_bf16(af3_, bfr[2], acc[(QM)*4+3][2],0,0,0);  \
  acc[(QM)*4+3][3] = __builtin_amdgcn_mfma_f32_16x16x32_bf16(af3_, bfr[3], acc[(QM)*4+3][3],0,0,0)

#define PHASE(T4, KK, QM, HSTAGE, LOADB)                                        \
  {                                                                             \
    const int slA_ = (((T4) + 2 * (KK)) & 7) * 8704;                            \
    bf16x8 af0_ = *(const bf16x8*)&L[slA_ + offA + (QM) * 2048 + 0 * 512];      \
    bf16x8 af1_ = *(const bf16x8*)&L[slA_ + offA + (QM) * 2048 + 1 * 512];      \
    bf16x8 af2_ = *(const bf16x8*)&L[slA_ + offA + (QM) * 2048 + 2 * 512];      \
    bf16x8 af3_ = *(const bf16x8*)&L[slA_ + offA + (QM) * 2048 + 3 * 512];      \
    if (LOADB) {                                                                \
      const int slB_ = (((T4) + 2 * (KK) + 1) & 7) * 8704;                      \
      bfr[0] = *(const bf16x8*)&L[slB_ + offB + 0 * 512];                       \
      bfr[1] = *(const bf16x8*)&L[slB_ + offB + 1 * 512];                       \
      bfr[2] = *(const bf16x8*)&L[slB_ + offB + 2 * 512];                       \
      bfr[3] = *(const bf16x8*)&L[slB_ + offB + 3 * 512];                       \
    }                                                                           \
    STAGE(HSTAGE);                                                              \
    PH_BAR();                                                                   \
    __builtin_amdgcn_s_setprio(1);                                              \
    MFMA16(QM);                                                                 \
    __builtin_amdgcn_s_setprio(0);                                              \
  }

  for (int t = 0; t < 16; ++t) {
    int t4 = t * 4;
    PHASE(t4, 0, 0, t4 + 6, 1);
    PH_BAR();
    PHASE(t4, 0, 1, t4 + 7, 0);
    PH_BAR();
    PHASE(t4, 1, 0, t4 + 8, 1);
    PH_BAR();
    PHASE(t4, 1, 1, t4 + 9, 0);
    // tile-boundary wait: keep newest 2 halves (4 loads) in flight; full drain before last
    if (t < 14)       { asm volatile("s_waitcnt vmcnt(4)" ::: "memory"); }
    else if (t == 14) { asm volatile("s_waitcnt vmcnt(0)" ::: "memory"); }
    PH_BAR();
  }
#undef PHASE
#undef MFMA16
#undef STAGE
#undef PH_BAR

  int matid = n0 >> 10;
  if (matid == 2) {
    // ---- V blocks: write V^T directly ([b,h,e,s]); replaces the old k_vt kernel ----
    // Per-wave LDS transpose in its own slot: rows e=0..63, stride 136 u16 (272B: 16B
    // aligned reads; 8B writes land 4 lanes/bank-group = pass floor). Then block-wide
    // coalesced 16B stores of s-contiguous runs.
    uint16_t* wbuf = &L[wave * 8704];
    #pragma unroll
    for (int mq = 0; mq < 8; mq++)
      #pragma unroll
      for (int nt = 0; nt < 4; nt++) {
        __align__(8) uint16_t t4v[4];
        #pragma unroll
        for (int r = 0; r < 4; r++) t4v[r] = f2b(acc[mq][nt][r]);
        int e = nt * 16 + l16;
        *(uint2*)&wbuf[e * 136 + mq * 16 + quad * 4] = *(uint2*)t4v;
      }
    __syncthreads();
    int hb = (n0 - 2048) >> 6;           // head base for this block (4 heads)
    int b = m0 >> 11, s0m = m0 & 2047;   // batch + s-offset (m0 never straddles a batch)
    #pragma unroll
    for (int i = 0; i < 16; i++) {
      int c = i * 512 + tid;             // 8192 chunks: 256 rows x 32 s-blocks of 8
      int row = c >> 5, sb = c & 31;
      int hl = row >> 6, e = row & 63;   // hl = source wave column (wc)
      int wsrc = (sb >> 4) * 4 + hl;     // source wave = wr(sb)*4 + wc
      uint4 d = *(const uint4*)&L[wsrc * 8704 + e * 136 + (sb & 15) * 8];
      *(uint4*)&vt[((size_t)(b * 16 + hb + hl) * 64 + e) * 2048 + s0m + sb * 8] = d;
    }
  } else {
    // ---- Q/K blocks: scatter to [b,h,s,e] with Q pre-scale ----
    float scale = (matid == 0) ? Q_SCALE : 1.0f;
    uint16_t* base = qk + (size_t)matid * QSLAB;
    int hh = ((n0 & 1023) >> 6) + wc;    // one head per wave-column (64 cols)
    #pragma unroll
    for (int mq = 0; mq < 8; mq++) {
      int m = m0 + wr * 128 + mq * 16 + quad * 4;
      int b = m >> 11, s = m & 2047;
      size_t rbase = ((size_t)(b * 16 + hh) * NS + s) * NHS;
      #pragma unroll
      for (int nt = 0; nt < 4; nt++)
        #pragma unroll
        for (int r = 0; r < 4; r++)
          base[rbase + (size_t)r * NHS + nt * 16 + l16] = f2b(acc[mq][nt][r] * scale);
    }
  }
}

#if HAVE_MFMA1K
// ---------------- kernel 2: causal attention, S^T trick + reg-prefetch double-buffer ----------------
// S^T = K.Q^T puts P^T directly in B-operand layout of 16x16x16 MFMA; O^T = V^T.P^T in regs.
// K/V^T tile kt+1 prefetched into VGPRs while computing tile kt; regs flushed to padded
// LDS between barriers. Global-load latency overlaps the whole compute phase.
__global__ __launch_bounds__(256, 4) void k_attn(
    const uint16_t* __restrict__ Q, const uint16_t* __restrict__ K,
    const uint16_t* __restrict__ VT, uint16_t* __restrict__ Y) {
  __shared__ __align__(16) uint16_t Ks[64][72];   // [key][e]
  __shared__ __align__(16) uint16_t Vs[64][72];   // [e][key]
  int bh = blockIdx.y;
  int b = bh >> 4, h = bh & 15;
  int ta = blockIdx.x;       // 0..15
  int tb = 31 - ta;          // 16..31
  const uint16_t* Qp = Q + (size_t)bh * (NS * NHS);
  const uint16_t* Kp = K + (size_t)bh * (NS * NHS);
  const uint16_t* Vp = VT + (size_t)bh * (NS * NHS);  // [e][key]
  int tid = threadIdx.x;
  int wv = tid >> 6, lane = tid & 63, quad = lane >> 4, l16 = lane & 15;

  // staging map: each thread covers u = tid and tid+256 (row = u>>3, 16B col = u&7)
  int row0 = tid >> 3, cg0 = tid & 7;
  int row1 = (tid + 256) >> 3, cg1 = tid & 7;

  // Q fragments from global; B operand of S^T = K.Q^T (n = q-row = l16)
  int rA = ta * 64 + wv * 16 + l16;
  int rB = tb * 64 + wv * 16 + l16;
  bf16x8 aqA0 = *(const bf16x8*)&Qp[(size_t)rA * NHS + quad * 8];
  bf16x8 aqA1 = *(const bf16x8*)&Qp[(size_t)rA * NHS + 32 + quad * 8];
  bf16x8 aqB0 = *(const bf16x8*)&Qp[(size_t)rB * NHS + quad * 8];
  bf16x8 aqB1 = *(const bf16x8*)&Qp[(size_t)rB * NHS + 32 + quad * 8];

  float lAs = 0.f, lBs = 0.f;          // per-lane row-sum (all p of a lane share q-row l16)
  floatx4 oA[4], oB[4];                // O^T accumulators, one per e-tile
  for (int et = 0; et < 4; et++) {
    oA[et] = (floatx4){0.f, 0.f, 0.f, 0.f};
    oB[et] = (floatx4){0.f, 0.f, 0.f, 0.f};
  }

  // prefetch tile 0 into registers
  uint4 rk0, rk1, rv0, rv1;
  rk0 = *(const uint4*)&Kp[(size_t)(0 * 64 + row0) * NHS + cg0 * 8];
  rk1 = *(const uint4*)&Kp[(size_t)(0 * 64 + row1) * NHS + cg1 * 8];
  rv0 = *(const uint4*)&Vp[(size_t)row0 * NS + 0 * 64 + cg0 * 8];
  rv1 = *(const uint4*)&Vp[(size_t)row1 * NS + 0 * 64 + cg1 * 8];

  for (int kt = 0; kt <= tb; kt++) {
    bool doA = (kt <= ta);  // uniform across block
    __syncthreads();        // readers of previous tile done
    *(uint4*)&Ks[row0][cg0 * 8] = rk0;
    *(uint4*)&Ks[row1][cg1 * 8] = rk1;
    *(uint4*)&Vs[row0][cg0 * 8] = rv0;
    *(uint4*)&Vs[row1][cg1 * 8] = rv1;
    __syncthreads();        // tile kt visible
    if (kt < tb) {          // issue prefetch of kt+1; consumed after next barrier
      rk0 = *(const uint4*)&Kp[(size_t)((kt + 1) * 64 + row0) * NHS + cg0 * 8];
      rk1 = *(const uint4*)&Kp[(size_t)((kt + 1) * 64 + row1) * NHS + cg1 * 8];
      rv0 = *(const uint4*)&Vp[(size_t)row0 * NS + (kt + 1) * 64 + cg0 * 8];
      rv1 = *(const uint4*)&Vp[(size_t)row1 * NS + (kt + 1) * 64 + cg1 * 8];
    }

    // ---- S^T tiles + mask + exp2 + pack (P^T lands in B-layout of K=16 MFMA) ----
    s16x4 pbA[4], pbB[4];
    for (int ct = 0; ct < 4; ct++) {
      bf16x8 kb0 = *(const bf16x8*)&Ks[ct * 16 + l16][quad * 8];
      bf16x8 kb1 = *(const bf16x8*)&Ks[ct * 16 + l16][32 + quad * 8];
      int key = kt * 64 + ct * 16 + quad * 4;
      floatx4 c = (floatx4){0.f, 0.f, 0.f, 0.f};
      c = __builtin_amdgcn_mfma_f32_16x16x32_bf16(kb0, aqB0, c, 0, 0, 0);
      c = __builtin_amdgcn_mfma_f32_16x16x32_bf16(kb1, aqB1, c, 0, 0, 0);
      for (int r = 0; r < 4; r++) {
        float s = (kt == tb && key + r > rB) ? NEG_BIG : c[r];
        float p = __builtin_amdgcn_exp2f(s);
        lBs += p;
        pbB[ct][r] = (short)f2b(p);
      }
      if (doA) {
        floatx4 d = (floatx4){0.f, 0.f, 0.f, 0.f};
        d = __builtin_amdgcn_mfma_f32_16x16x32_bf16(kb0, aqA0, d, 0, 0, 0);
        d = __builtin_amdgcn_mfma_f32_16x16x32_bf16(kb1, aqA1, d, 0, 0, 0);
        for (int r = 0; r < 4; r++) {
          float s = (kt == ta && key + r > rA) ? NEG_BIG : d[r];
          float p = __builtin_amdgcn_exp2f(s);
          lAs += p;
          pbA[ct][r] = (short)f2b(p);
        }
      }
    }
    // ---- O^T += V^T . P^T (A-frag = 4 keys of V^T via ds_read_b64, shared A/B) ----
    for (int et = 0; et < 4; et++)
      for (int ct = 0; ct < 4; ct++) {
        s16x4 va = *(const s16x4*)&Vs[et * 16 + l16][ct * 16 + quad * 4];
        oB[et] = __builtin_amdgcn_mfma_f32_16x16x16bf16_1k(va, pbB[ct], oB[et], 0, 0, 0);
        if (doA)
          oA[et] = __builtin_amdgcn_mfma_f32_16x16x16bf16_1k(va, pbA[ct], oA[et], 0, 0, 0);
      }
  }
  // ---- reduce row-sums across the 4 quads, normalize, packed store ----
  lAs += __shfl_xor(lAs, 16, 64); lAs += __shfl_xor(lAs, 32, 64);
  lBs += __shfl_xor(lBs, 16, 64); lBs += __shfl_xor(lBs, 32, 64);
  float invA = 1.f / lAs, invB = 1.f / lBs;
  uint16_t* yb = Y + (size_t)b * NS * ND + (size_t)h * NHS;
  for (int et = 0; et < 4; et++) {
    __align__(8) uint16_t tA[4], tB[4];
    for (int r = 0; r < 4; r++) {
      tA[r] = f2b(oA[et][r] * invA);
      tB[r] = f2b(oB[et][r] * invB);
    }
    *(uint2*)&yb[(size_t)rA * ND + et * 16 + quad * 4] = *(uint2*)tA;
    *(uint2*)&yb[(size_t)rB * ND + et * 16 + quad * 4] = *(uint2*)tB;
  }
}
#else
// ---------------- fallback: round-8 k_attn (LDS-staged K/V + P round-trip) ----------------
__global__ __launch_bounds__(256) void k_attn(
    const uint16_t* __restrict__ Q, const uint16_t* __restrict__ K,
    const uint16_t* __restrict__ VT, uint16_t* __restrict__ Y) {
  __shared__ __align__(16) uint16_t Ks[64][72];
  __shared__ __align__(16) uint16_t Vs[64][72];
  __shared__ __align__(16) uint16_t Ps[4][2][16][72];
  int bh = blockIdx.y;
  int b = bh >> 4, h = bh & 15;
  int ta = blockIdx.x;
  int tb = 31 - ta;
  const uint16_t* Qp = Q + (size_t)bh * (NS * NHS);
  const uint16_t* Kp = K + (size_t)bh * (NS * NHS);
  const uint16_t* Vp = VT + (size_t)bh * (NS * NHS);
  int tid = threadIdx.x;
  int wv = tid >> 6, lane = tid & 63, quad = lane >> 4, l16 = lane & 15;

  int rA = ta * 64 + wv * 16 + l16;
  int rB = tb * 64 + wv * 16 + l16;
  bf16x8 aqA0 = *(const bf16x8*)&Qp[(size_t)rA * NHS + quad * 8];
  bf16x8 aqA1 = *(const bf16x8*)&Qp[(size_t)rA * NHS + 32 + quad * 8];
  bf16x8 aqB0 = *(const bf16x8*)&Qp[(size_t)rB * NHS + quad * 8];
  bf16x8 aqB1 = *(const bf16x8*)&Qp[(size_t)rB * NHS + 32 + quad * 8];

  float lA[4] = {0.f, 0.f, 0.f, 0.f}, lB[4] = {0.f, 0.f, 0.f, 0.f};
  floatx4 oA[4], oB[4];
  for (int ct = 0; ct < 4; ct++) {
    oA[ct] = (floatx4){0.f, 0.f, 0.f, 0.f};
    oB[ct] = (floatx4){0.f, 0.f, 0.f, 0.f};
  }
  for (int kt = 0; kt <= tb; kt++) {
    bool doA = (kt <= ta);
    __syncthreads();
    for (int u = tid; u < 512; u += 256) {
      int row = u >> 3, cg = u & 7;
      *(uint4*)&Ks[row][cg * 8] =
          *(const uint4*)&Kp[(size_t)(kt * 64 + row) * NHS + cg * 8];
    }
    for (int u = tid; u < 512; u += 256) {
      int row = u >> 3, cg = u & 7;
      *(uint4*)&Vs[row][cg * 8] =
          *(const uint4*)&Vp[(size_t)row * NS + kt * 64 + cg * 8];
    }
    __syncthreads();
    floatx4 sA[4], sB[4];
    for (int ct = 0; ct < 4; ct++) {
      bf16x8 kb0 = *(const bf16x8*)&Ks[ct * 16 + l16][quad * 8];
      bf16x8 kb1 = *(const bf16x8*)&Ks[ct * 16 + l16][32 + quad * 8];
      floatx4 c = (floatx4){0.f, 0.f, 0.f, 0.f};
      c = __builtin_amdgcn_mfma_f32_16x16x32_bf16(aqB0, kb0, c, 0, 0, 0);
      c = __builtin_amdgcn_mfma_f32_16x16x32_bf16(aqB1, kb1, c, 0, 0, 0);
      sB[ct] = c;
      if (doA) {
        floatx4 d = (floatx4){0.f, 0.f, 0.f, 0.f};
        d = __builtin_amdgcn_mfma_f32_16x16x32_bf16(aqA0, kb0, d, 0, 0, 0);
        d = __builtin_amdgcn_mfma_f32_16x16x32_bf16(aqA1, kb1, d, 0, 0, 0);
        sA[ct] = d;
      }
    }
    if (kt == tb) {
      int qrb = tb * 64 + wv * 16 + quad * 4;
      for (int ct = 0; ct < 4; ct++) {
        int kg = kt * 64 + ct * 16 + l16;
        for (int r = 0; r < 4; r++)
          sB[ct][r] = (kg <= qrb + r) ? sB[ct][r] : NEG_BIG;
      }
    }
    if (doA && kt == ta) {
      int qrb = ta * 64 + wv * 16 + quad * 4;
      for (int ct = 0; ct < 4; ct++) {
        int kg = kt * 64 + ct * 16 + l16;
        for (int r = 0; r < 4; r++)
          sA[ct][r] = (kg <= qrb + r) ? sA[ct][r] : NEG_BIG;
      }
    }
    for (int ct = 0; ct < 4; ct++)
      for (int r = 0; r < 4; r++) {
        float p = __builtin_amdgcn_exp2f(sB[ct][r]);
        lB[r] += p;
        Ps[wv][1][quad * 4 + r][ct * 16 + l16] = f2b(p);
      }
    if (doA)
      for (int ct = 0; ct < 4; ct++)
        for (int r = 0; r < 4; r++) {
          float p = __builtin_amdgcn_exp2f(sA[ct][r]);
          lA[r] += p;
          Ps[wv][0][quad * 4 + r][ct * 16 + l16] = f2b(p);
        }
    bf16x8 apB0 = *(const bf16x8*)&Ps[wv][1][l16][quad * 8];
    bf16x8 apB1 = *(const bf16x8*)&Ps[wv][1][l16][32 + quad * 8];
    bf16x8 apA0, apA1;
    if (doA) {
      apA0 = *(const bf16x8*)&Ps[wv][0][l16][quad * 8];
      apA1 = *(const bf16x8*)&Ps[wv][0][l16][32 + quad * 8];
    }
    for (int ct = 0; ct < 4; ct++) {
      bf16x8 vb0 = *(const bf16x8*)&Vs[ct * 16 + l16][quad * 8];
      bf16x8 vb1 = *(const bf16x8*)&Vs[ct * 16 + l16][32 + quad * 8];
      oB[ct] = __builtin_amdgcn_mfma_f32_16x16x32_bf16(apB0, vb0, oB[ct], 0, 0, 0);
      oB[ct] = __builtin_amdgcn_mfma_f32_16x16x32_bf16(apB1, vb1, oB[ct], 0, 0, 0);
      if (doA) {
        oA[ct] = __builtin_amdgcn_mfma_f32_16x16x32_bf16(apA0, vb0, oA[ct], 0, 0, 0);
        oA[ct] = __builtin_amdgcn_mfma_f32_16x16x32_bf16(apA1, vb1, oA[ct], 0, 0, 0);
      }
    }
  }
  for (int off = 1; off < 16; off <<= 1)
    for (int r = 0; r < 4; r++) {
      lA[r] += __shfl_xor(lA[r], off, 64);
      lB[r] += __shfl_xor(lB[r], off, 64);
    }
  uint16_t* yb = Y + (size_t)b * NS * ND + (size_t)h * NHS;
  for (int ct = 0; ct < 4; ct++)
    for (int r = 0; r < 4; r++) {
      int sA_ = ta * 64 + wv * 16 + quad * 4 + r;
      int sB_ = tb * 64 + wv * 16 + quad * 4 + r;
      yb[(size_t)sA_ * ND + ct * 16 + l16] = f2b(oA[ct][r] / lA[r]);
      yb[(size_t)sB_ * ND + ct * 16 + l16] = f2b(oB[ct][r] / lB[r]);
    }
}
#endif

// ---------------- kernel 3: output projection + bias, m97-style (fp32 out) ----------------
__global__ __launch_bounds__(256) void k_proj(
    const uint16_t* __restrict__ y, const uint16_t* __restrict__ wot,
    const float* __restrict__ bo, float* __restrict__ out) {
  __shared__ __align__(16) uint16_t As[128 * 64];
  __shared__ __align__(16) uint16_t Bs[128 * 64];
  int m0 = blockIdx.x * 128;
  int n0 = blockIdx.y * 128;
  int tid = threadIdx.x;
  int wv = tid >> 6, lane = tid & 63, quad = lane >> 4, l16 = lane & 15;
  int wr = wv >> 1, wc = wv & 1;
  int srow = lane >> 3, scol = lane & 7;

  floatx4 acc[4][4];
  for (int i = 0; i < 4; i++)
    for (int j = 0; j < 4; j++) acc[i][j] = (floatx4){0.f, 0.f, 0.f, 0.f};

  for (int k0 = 0; k0 < ND; k0 += 64) {
    __syncthreads();
    for (int j = 0; j < 4; j++) {
      int rg = wv * 4 + j;
      int r = rg * 8 + srow;
      gll16(&y[(size_t)(m0 + r) * ND + k0 + scol * 8], &As[rg * 512]);
      gll16(&wot[(size_t)(n0 + r) * ND + k0 + scol * 8], &Bs[rg * 512]);
    }
    __syncthreads();
    for (int kk = 0; kk < 2; kk++) {
      bf16x8 af[4], bfr[4];
      for (int t = 0; t < 4; t++) {
        af[t]  = *(const bf16x8*)&As[(wr * 64 + t * 16 + l16) * 64 + kk * 32 + quad * 8];
        bfr[t] = *(const bf16x8*)&Bs[(wc * 64 + t * 16 + l16) * 64 + kk * 32 + quad * 8];
      }
      for (int mt = 0; mt < 4; mt++)
        for (int nt = 0; nt < 4; nt++)
          acc[mt][nt] = __builtin_amdgcn_mfma_f32_16x16x32_bf16(af[mt], bfr[nt], acc[mt][nt], 0, 0, 0);
    }
  }
  for (int mt = 0; mt < 4; mt++)
    for (int nt = 0; nt < 4; nt++)
      for (int r = 0; r < 4; r++) {
        int s = m0 + wr * 64 + mt * 16 + quad * 4 + r;
        int n = n0 + wc * 64 + nt * 16 + l16;
        out[(size_t)s * ND + n] = acc[mt][nt][r] + bo[n];
      }
}

extern "C" void kernel_launch(void* const* d_in, const int* in_sizes, int n_in,
                              void* d_out, int out_size, void* d_ws, size_t ws_size,
                              hipStream_t stream) {
  const float* x  = (const float*)d_in[0];
  const float* Wq = (const float*)d_in[1];
  const float* Wk = (const float*)d_in[2];
  const float* Wv = (const float*)d_in[3];
  const float* Wo = (const float*)d_in[4];
  const float* bo = (const float*)d_in[5];
  uint16_t* ws = (uint16_t*)d_ws;

  uint16_t* wt = ws;                       // 4 * WSLAB bf16 (Wq_t, Wk_t, Wv_t, Wo_t)
  uint16_t* xb = ws + 4 * WSLAB;           // XSLAB bf16
  uint16_t* q  = xb + XSLAB;               // QSLAB each; k contiguous after q
  uint16_t* k  = q + QSLAB;
  uint16_t* vt = k + QSLAB;                // QSLAB (V transposed, written by k_qkv)
  uint16_t* y  = vt + QSLAB;

  k_prep<<<dim3(5120), dim3(256), 0, stream>>>(x, Wq, Wk, Wv, Wo, xb, wt);
  k_qkv<<<dim3(384), dim3(512), 0, stream>>>(xb, wt, q, vt);
  k_attn<<<dim3(16, NB * NH), dim3(256), 0, stream>>>(q, k, vt, y);
  k_proj<<<dim3(64, 8), dim3(256), 0, stream>>>(y, wt + 3 * WSLAB, bo, (float*)d_out);
}